// Round 15
// baseline (1229.562 us; speedup 1.0000x reference)
//
#include <hip/hip_runtime.h>

typedef unsigned short u16;
typedef unsigned int u32;
typedef float f32x4 __attribute__((ext_vector_type(4)));
typedef __bf16 bf16x8 __attribute__((ext_vector_type(8)));

// B=256, T=512, FIN=128, H=256, 3H=768
#define TB 256
#define TT 512
#define TC 64
#define NCHUNK 8
#define NGEMMB 160  // persistent gemm-producer blocks (grid = 16 + 160 = 176 <= CU count)

__device__ __forceinline__ u16 f2b(float f) {
  u32 x = __float_as_uint(f);
  return (u16)((x + 0x7fffu + ((x >> 16) & 1u)) >> 16);
}
__device__ __forceinline__ u32 pkbf(float a, float b) {  // RNE, bit-identical to f2b pair pack
  u32 r;
  asm("v_cvt_pk_bf16_f32 %0, %1, %2" : "=v"(r) : "v"(a), "v"(b));
  return r;
}
__device__ __forceinline__ float blo(u32 u) { return __uint_as_float(u << 16); }
__device__ __forceinline__ float bhi(u32 u) { return __uint_as_float(u & 0xffff0000u); }
__device__ __forceinline__ float sigm(float x) {
  return __builtin_amdgcn_rcpf(1.f + __expf(-x));
}

// in: (K,N) fp32 row-major -> out: (N,K) bf16 row-major (B^T for GEMM)
__global__ void tcast_kernel(const float* __restrict__ in, u16* __restrict__ out, int K, int N) {
  int idx = blockIdx.x * blockDim.x + threadIdx.x;
  if (idx < K * N) {
    int k = idx / N, n = idx % N;
    out[n * K + k] = f2b(in[idx]);
  }
}

// Wr (256,768) -> permuted B^T: pcol(w,nt,l15) holds original col n = gate*256 + 32w + 2*l15 + grp,
// nt = gate*2+grp. Wave w then owns gate triples (z,r,h) for h-cols {32w+2*l15+grp}.
__global__ void wrperm_kernel(const float* __restrict__ in, u16* __restrict__ out) {
  int idx = blockIdx.x * blockDim.x + threadIdx.x;
  if (idx < 256 * 768) {
    int k = idx / 768, n = idx % 768;
    int gate = n >> 8, c = n & 255;
    int w = c >> 5, cc = c & 31, l15 = cc >> 1, grp = cc & 1;
    int nt = gate * 2 + grp;
    out[((((w * 6 + nt) << 4) + l15) << 8) + k] = f2b(in[idx]);
  }
}

// biasMod = bi + [br_z, br_r, 0]
__global__ void biasmod_kernel(const float* __restrict__ bi, const float* __restrict__ br,
                               float* __restrict__ bm) {
  int n = blockIdx.x * blockDim.x + threadIdx.x;
  if (n < 768) bm[n] = bi[n] + (n < 512 ? br[n] : 0.f);
}

// ---------------- gemm tile (works with 256- or 512-thread blocks; tid<256 active) ----------------
// CASTA=1: A fp32, converted during staging (bit-identical to separate-cast path).
// MODE 0: A rows = bm*128+r, relu, C ldc=256. MODE 1: A rows = (2bm+(r>>6))*512+t0+(r&63),
// C rows = bm*128+r natural chunk layout, ldc=768.
template<int KT, int MODE, int CASTA>
__device__ void gemm_tile(char* smem_c, const void* __restrict__ Av, const u16* __restrict__ Bt,
                          const float* __restrict__ bias, u16* __restrict__ C, int t0,
                          int bm, int bn) {
  constexpr int K = KT * 32;
  const u16* A = (const u16*)Av;
  const float* Af = (const float*)Av;
  u16* As = (u16*)smem_c;             // [128][40]
  u16* Bs = (u16*)(smem_c + 10240);   // [128][40]
  const int tid = threadIdx.x;
  const bool act = (tid < 256);
  const int lane = tid & 63, wid = tid >> 6;
  const int l15 = lane & 15, l4 = lane >> 4;
  const int qm = ((wid & 3) >> 1) * 64, qn = (wid & 1) * 64;

  const int c0 = tid & 255, c1 = (tid & 255) + 256;
  const int r0 = c0 >> 2, r1 = c1 >> 2;
  const int ar0 = (MODE == 0) ? (bm * 128 + r0) : ((2 * bm + (r0 >> 6)) * 512 + t0 + (r0 & 63));
  const int ar1 = (MODE == 0) ? (bm * 128 + r1) : ((2 * bm + (r1 >> 6)) * 512 + t0 + (r1 & 63));
  const size_t ga0 = (size_t)ar0 * K + (c0 & 3) * 8;
  const size_t ga1 = (size_t)ar1 * K + (c1 & 3) * 8;
  const size_t gb0 = (size_t)(bn * 128 + r0) * K + (c0 & 3) * 8;
  const size_t gb1 = (size_t)(bn * 128 + r1) * K + (c1 & 3) * 8;
  const int sa0 = r0 * 40 + (c0 & 3) * 8;
  const int sa1 = r1 * 40 + (c1 & 3) * 8;

#define LOADA(ga, ko, dst)                                                       \
  if (CASTA) {                                                                   \
    const float* p = Af + (ga) + (ko);                                           \
    const f32x4 v0 = *(const f32x4*)(p);                                         \
    const f32x4 v1 = *(const f32x4*)(p + 4);                                     \
    (dst).x = pkbf(v0[0], v0[1]); (dst).y = pkbf(v0[2], v0[3]);                  \
    (dst).z = pkbf(v1[0], v1[1]); (dst).w = pkbf(v1[2], v1[3]);                  \
  } else {                                                                       \
    (dst) = *(const uint4*)(A + (ga) + (ko));                                    \
  }

  uint4 ra0 = {}, ra1 = {}, rb0 = {}, rb1 = {};
  if (act) {
    LOADA(ga0, 0, ra0);
    LOADA(ga1, 0, ra1);
    rb0 = *(const uint4*)(Bt + gb0);
    rb1 = *(const uint4*)(Bt + gb1);
  }
  f32x4 acc[4][4] = {};

  for (int kt = 0; kt < KT; ++kt) {
    __syncthreads();
    if (act) {
      *(uint4*)(As + sa0) = ra0;
      *(uint4*)(As + sa1) = ra1;
      *(uint4*)(Bs + sa0) = rb0;
      *(uint4*)(Bs + sa1) = rb1;
    }
    __syncthreads();
    if (act) {
      if (kt + 1 < KT) {
        const int ko = (kt + 1) * 32;
        LOADA(ga0, ko, ra0);
        LOADA(ga1, ko, ra1);
        rb0 = *(const uint4*)(Bt + gb0 + ko);
        rb1 = *(const uint4*)(Bt + gb1 + ko);
      }
      bf16x8 af[4], bfr[4];
#pragma unroll
      for (int mt = 0; mt < 4; ++mt)
        af[mt] = *(const bf16x8*)(As + (qm + mt * 16 + l15) * 40 + l4 * 8);
#pragma unroll
      for (int nt = 0; nt < 4; ++nt)
        bfr[nt] = *(const bf16x8*)(Bs + (qn + nt * 16 + l15) * 40 + l4 * 8);
#pragma unroll
      for (int mt = 0; mt < 4; ++mt)
#pragma unroll
        for (int nt = 0; nt < 4; ++nt)
          acc[mt][nt] = __builtin_amdgcn_mfma_f32_16x16x32_bf16(af[mt], bfr[nt], acc[mt][nt], 0, 0, 0);
    }
  }
#undef LOADA

  if (act) {
#pragma unroll
    for (int mt = 0; mt < 4; ++mt)
#pragma unroll
      for (int nt = 0; nt < 4; ++nt) {
        const int n = bn * 128 + qn + nt * 16 + l15;
        const float bv = bias[n];
#pragma unroll
        for (int j = 0; j < 4; ++j) {
          const int rloc = qm + mt * 16 + l4 * 4 + j;  // D: row=(lane>>4)*4+j, col=lane&15
          float v = acc[mt][nt][j] + bv;
          if (MODE == 0) {
            v = fmaxf(v, 0.f);
            C[(size_t)(bm * 128 + rloc) * 256 + n] = f2b(v);
          } else {
            C[((size_t)bm * 128 + rloc) * 768 + n] = f2b(v);
          }
        }
      }
  }
}

// prologue wrappers (256 threads, high occupancy)
__global__ __launch_bounds__(256) void gemm1_kernel(const float* __restrict__ x,
                                                    const u16* __restrict__ W1T,
                                                    const float* __restrict__ b1,
                                                    u16* __restrict__ h1) {
  __shared__ alignas(16) char smem_c[20480];
  gemm_tile<4, 0, 1>(smem_c, x, W1T, b1, h1, 0, blockIdx.x, blockIdx.y);
}
__global__ __launch_bounds__(256) void gemm2_kernel(const u16* __restrict__ h1,
                                                    const u16* __restrict__ WkT,
                                                    const float* __restrict__ biasM,
                                                    u16* __restrict__ xg, int t0) {
  __shared__ alignas(16) char smem_c[20480];
  gemm_tile<8, 1, 0>(smem_c, h1, WkT, biasM, xg, t0, blockIdx.x, blockIdx.y);
}

// ---------------- persistent producer-consumer kernel ----------------
// 176 blocks x 512 threads, 82KB LDS => 1 block/CU => all blocks co-resident (176 <= 256 CUs).
// Blocks 0-15: GRU, all 8 chunks, bw/h persistent. Blocks 16-175: gemm2 producers for
// chunks 1..7 (~4.8 tiles each per chunk). Sync: device-scope atomic counters.
//   ctrX[c] (=NGEMMB when chunk c's xg writes are globally visible)  - gemm releases, GRU acquires
//   ctrG[c] (=16 when GRU finished READING chunk c)                  - GRU releases, gemm acquires
//     (gemm must wait ctrG[c-2] before overwriting xg[c&1], the buffer chunk c-2 was read from)
// Deadlock-free: GRU c=0 and gemm c=1 start unblocked; induction on c; producers never wait on
// anything newer than GRU c-2; all blocks co-resident.
__global__ __launch_bounds__(512, 1) void persist_kernel(
    u16* __restrict__ xg0, u16* __restrict__ xg1,
    const u16* __restrict__ WrP, const float* __restrict__ br,
    float* __restrict__ hstate, const u16* __restrict__ h1,
    const u16* __restrict__ WkT, const float* __restrict__ biasM,
    int* ctr) {
  __shared__ alignas(16) char smem_c[82048];
  const int tid = threadIdx.x;
  const int bid = blockIdx.x;
  int* ctrX = ctr;        // [8]
  int* ctrG = ctr + 8;    // [8]

  if (bid < 16) {
    // ---------------- GRU: all chunks, state persistent ----------------
    u16* hb0 = (u16*)smem_c;              // 16*264 u16 - ping (h bf16)
    u16* hb1 = (u16*)(smem_c + 8448);     // pong
    u16* xs0 = (u16*)(smem_c + 16896);    // 16*776 u16 xq stage - ping
    u16* xs1 = (u16*)(smem_c + 41728);    // pong
    const int g = bid;
    const int lane = tid & 63, wid = tid >> 6;
    const int l15 = lane & 15, l4 = lane >> 4;

    bf16x8 bw[8][6];
#pragma unroll
    for (int kk = 0; kk < 8; ++kk)
#pragma unroll
      for (int nt = 0; nt < 6; ++nt)
        bw[kk][nt] = *(const bf16x8*)(WrP + ((((wid * 6 + nt) << 4) + l15) << 8) + kk * 32 + l4 * 8);

    const int cbase = wid * 32 + l15 * 2;
    const float brh0 = br[512 + cbase];
    const float brh1 = br[512 + cbase + 1];
    const int rs = tid >> 5, ksl = (tid & 31) * 8;

    f32x4 h0v = {0.f, 0.f, 0.f, 0.f}, h1v = {0.f, 0.f, 0.f, 0.f};
#pragma unroll
    for (int j = 0; j < 4; ++j)
      *(u32*)(hb0 + (l4 * 4 + j) * 264 + cbase) = 0u;

    for (int c = 0; c < NCHUNK; ++c) {
      if (c > 0) {  // acquire chunk c's xg
        if (tid == 0)
          while (atomicAdd(&ctrX[c], 0) < NGEMMB) __builtin_amdgcn_s_sleep(16);
        __syncthreads();
        __threadfence();  // every thread: invalidate L1 before re-reading recycled buffer
      }
      const u16* xrd = (c & 1) ? xg1 : xg0;
      const u16* xg_row = xrd + (size_t)(g * 16 + rs) * TC * 768 + ksl;
      u16* xw0 = xs0 + rs * 776 + ksl;
      u16* xw1 = xs1 + rs * 776 + ksl;

      {  // pre-stage step 0 of this chunk into xs0
        const uint4 s0 = *(const uint4*)(xg_row);
        const uint4 s1 = *(const uint4*)(xg_row + 256);
        const uint4 s2 = *(const uint4*)(xg_row + 512);
        *(uint4*)(xw0) = s0;
        *(uint4*)(xw0 + 256) = s1;
        *(uint4*)(xw0 + 512) = s2;
      }
      __syncthreads();

#define GRU_STEP(SRC, DST, XRD, XWR, TL)                                                    \
  {                                                                                         \
    const int tn = ((TL) + 1 < TC) ? ((TL) + 1) : (TC - 1);                                 \
    const u16* xq = xg_row + (size_t)tn * 768;                                              \
    const uint4 s0 = *(const uint4*)(xq);                                                   \
    const uint4 s1 = *(const uint4*)(xq + 256);                                             \
    const uint4 s2 = *(const uint4*)(xq + 512);                                             \
    f32x4 a0 = {}, a2 = {}, a4 = {};                                                        \
    _Pragma("unroll")                                                                       \
    for (int kk = 0; kk < 8; ++kk) {                                                        \
      const bf16x8 a = *(const bf16x8*)((SRC) + l15 * 264 + kk * 32 + l4 * 8);              \
      a0 = __builtin_amdgcn_mfma_f32_16x16x32_bf16(a, bw[kk][0], a0, 0, 0, 0);              \
      a2 = __builtin_amdgcn_mfma_f32_16x16x32_bf16(a, bw[kk][2], a2, 0, 0, 0);              \
      a4 = __builtin_amdgcn_mfma_f32_16x16x32_bf16(a, bw[kk][4], a4, 0, 0, 0);              \
    }                                                                                       \
    u32 xz_[4], xr_[4], xh_[4];                                                             \
    _Pragma("unroll")                                                                       \
    for (int j = 0; j < 4; ++j) {                                                           \
      const u16* xr2 = (XRD) + (l4 * 4 + j) * 776 + cbase;                                  \
      xz_[j] = *(const u32*)(xr2);                                                          \
      xr_[j] = *(const u32*)(xr2 + 256);                                                    \
      xh_[j] = *(const u32*)(xr2 + 512);                                                    \
    }                                                                                       \
    f32x4 a1 = {}, a3 = {}, a5 = {};                                                        \
    _Pragma("unroll")                                                                       \
    for (int kk = 0; kk < 8; ++kk) {                                                        \
      const bf16x8 a = *(const bf16x8*)((SRC) + l15 * 264 + kk * 32 + l4 * 8);              \
      a1 = __builtin_amdgcn_mfma_f32_16x16x32_bf16(a, bw[kk][1], a1, 0, 0, 0);              \
      a3 = __builtin_amdgcn_mfma_f32_16x16x32_bf16(a, bw[kk][3], a3, 0, 0, 0);              \
      a5 = __builtin_amdgcn_mfma_f32_16x16x32_bf16(a, bw[kk][5], a5, 0, 0, 0);              \
    }                                                                                       \
    *(uint4*)(XWR) = s0;                                                                    \
    *(uint4*)((XWR) + 256) = s1;                                                            \
    *(uint4*)((XWR) + 512) = s2;                                                            \
    _Pragma("unroll")                                                                       \
    for (int j = 0; j < 4; ++j) {                                                           \
      const float z0 = sigm(blo(xz_[j]) + a0[j]);                                           \
      const float r0 = sigm(blo(xr_[j]) + a2[j]);                                           \
      const float hh0 = fmaxf(fmaf(r0, a4[j] + brh0, blo(xh_[j])), 0.f);                    \
      h0v[j] = fmaf(z0, h0v[j] - hh0, hh0);                                                 \
    }                                                                                       \
    _Pragma("unroll")                                                                       \
    for (int j = 0; j < 4; ++j) {                                                           \
      const float z1 = sigm(bhi(xz_[j]) + a1[j]);                                           \
      const float r1 = sigm(bhi(xr_[j]) + a3[j]);                                           \
      const float hh1 = fmaxf(fmaf(r1, a5[j] + brh1, bhi(xh_[j])), 0.f);                    \
      h1v[j] = fmaf(z1, h1v[j] - hh1, hh1);                                                 \
      *(u32*)((DST) + (l4 * 4 + j) * 264 + cbase) = pkbf(h0v[j], h1v[j]);                   \
    }                                                                                       \
    __syncthreads();                                                                        \
  }

      for (int tl = 0; tl < TC; tl += 2) {
        GRU_STEP(hb0, hb1, xs0, xw1, tl);
        GRU_STEP(hb1, hb0, xs1, xw0, tl + 1);
      }
#undef GRU_STEP

      // release: chunk c fully read -> its xg buffer may be overwritten (by chunk c+2)
      __threadfence();
      __syncthreads();
      if (tid == 0) atomicAdd(&ctrG[c], 1);
    }

    // persist final state for out_kernel
#pragma unroll
    for (int j = 0; j < 4; ++j) {
      float2 st = {h0v[j], h1v[j]};
      *(float2*)(hstate + ((size_t)g * 16 + l4 * 4 + j) * 256 + cbase) = st;
    }
  } else {
    // ---------------- gemm2 producers: chunks 1..7 ----------------
    const int pid = bid - 16;  // 0..NGEMMB-1
    for (int c = 1; c < NCHUNK; ++c) {
      if (c >= 2) {  // buffer safety: GRU must be done READING chunk c-2 (same buffer)
        if (tid == 0)
          while (atomicAdd(&ctrG[c - 2], 0) < 16) __builtin_amdgcn_s_sleep(16);
        __syncthreads();
        __threadfence();
      }
      u16* xwr = (c & 1) ? xg1 : xg0;
      for (int tix = pid; tix < 768; tix += NGEMMB)
        gemm_tile<8, 1, 0>(smem_c, h1, WkT, biasM, xwr, c * TC, tix & 127, tix >> 7);
      // release: this block's chunk-c writes visible device-wide
      __threadfence();
      __syncthreads();
      if (tid == 0) atomicAdd(&ctrX[c], 1);
    }
  }
}

// ---------------- output: y = [h,h] @ W2 + b2 = h @ (W2_top + W2_bot) + b2 ----------------
__global__ void out_kernel(const float* __restrict__ h, const float* __restrict__ W2,
                           const float* __restrict__ b2, float* __restrict__ y) {
  const int bb = blockIdx.x, j = threadIdx.x;  // 256 blocks x 128 threads
  const float* hr = h + (size_t)bb * 256;
  float s = b2[j];
  for (int i = 0; i < 256; ++i)
    s = fmaf(hr[i], W2[i * 128 + j] + W2[(i + 256) * 128 + j], s);
  y[(size_t)bb * 128 + j] = s;
}

extern "C" void kernel_launch(void* const* d_in, const int* in_sizes, int n_in,
                              void* d_out, int out_size, void* d_ws, size_t ws_size,
                              hipStream_t stream) {
  const float* x  = (const float*)d_in[0];
  const float* W1 = (const float*)d_in[1];
  const float* b1 = (const float*)d_in[2];
  const float* Wk = (const float*)d_in[3];
  const float* Wr = (const float*)d_in[4];
  const float* bi = (const float*)d_in[5];
  const float* br = (const float*)d_in[6];
  const float* W2 = (const float*)d_in[7];
  const float* b2 = (const float*)d_in[8];
  float* y = (float*)d_out;

  // workspace: ~118.6 MB total (R13 layout + 4KB counter region)
  const size_t NEED = 67108864ull + 25165824ull + 25165824ull + 65536ull + 393216ull +
                      393216ull + 262144ull + 4096ull + 4096ull;
  if (ws_size < NEED) return;

  char* ws = (char*)d_ws;
  u16* h1    = (u16*)ws;  ws += 67108864;   // (131072,256) bf16
  u16* xg0   = (u16*)ws;  ws += 25165824;   // (256,64,768) bf16 chunk buffer 0
  u16* xg1   = (u16*)ws;  ws += 25165824;   // chunk buffer 1
  u16* W1T   = (u16*)ws;  ws += 65536;      // (256,128) bf16
  u16* WkT   = (u16*)ws;  ws += 393216;     // (768,256) bf16
  u16* WrP   = (u16*)ws;  ws += 393216;     // permuted Wr^T (768,256) bf16
  float* hstate = (float*)ws; ws += 262144; // (256,256) f32 final GRU state
  float* biasM  = (float*)ws; ws += 4096;   // 768 f32
  int* ctr   = (int*)ws;                    // ctrX[8] + ctrG[8]

  hipMemsetAsync(ctr, 0, 64, stream);
  tcast_kernel<<<128, 256, 0, stream>>>(W1, W1T, 128, 256);
  tcast_kernel<<<768, 256, 0, stream>>>(Wk, WkT, 256, 768);
  wrperm_kernel<<<768, 256, 0, stream>>>(Wr, WrP);
  biasmod_kernel<<<3, 256, 0, stream>>>(bi, br, biasM);
  gemm1_kernel<<<dim3(1024, 2), 256, 0, stream>>>(x, W1T, b1, h1);
  gemm2_kernel<<<dim3(128, 6), 256, 0, stream>>>(h1, WkT, biasM, xg0, 0);  // chunk 0
  persist_kernel<<<16 + NGEMMB, 512, 0, stream>>>(xg0, xg1, WrP, br, hstate, h1, WkT, biasM, ctr);
  out_kernel<<<256, 128, 0, stream>>>(hstate, W2, b2, y);
}

// Round 16
// 965.593 us; speedup vs baseline: 1.2734x; 1.2734x over previous
//
#include <hip/hip_runtime.h>

typedef unsigned short u16;
typedef unsigned int u32;
typedef float f32x4 __attribute__((ext_vector_type(4)));
typedef __bf16 bf16x8 __attribute__((ext_vector_type(8)));

// B=256, T=512, FIN=128, H=256, 3H=768
#define TB 256
#define TT 512

__device__ __forceinline__ u16 f2b(float f) {
  u32 x = __float_as_uint(f);
  return (u16)((x + 0x7fffu + ((x >> 16) & 1u)) >> 16);
}
__device__ __forceinline__ u32 pkbf(float a, float b) {  // RNE, bit-identical to f2b pair pack
  u32 r;
  asm("v_cvt_pk_bf16_f32 %0, %1, %2" : "=v"(r) : "v"(a), "v"(b));
  return r;
}
__device__ __forceinline__ float blo(u32 u) { return __uint_as_float(u << 16); }
__device__ __forceinline__ float bhi(u32 u) { return __uint_as_float(u & 0xffff0000u); }
__device__ __forceinline__ float sigm(float x) {
  return __builtin_amdgcn_rcpf(1.f + __expf(-x));
}

// in: (K,N) fp32 row-major -> out: (N,K) bf16 row-major (B^T for GEMM)
__global__ void tcast_kernel(const float* __restrict__ in, u16* __restrict__ out, int K, int N) {
  int idx = blockIdx.x * blockDim.x + threadIdx.x;
  if (idx < K * N) {
    int k = idx / N, n = idx % N;
    out[n * K + k] = f2b(in[idx]);
  }
}

// Wr (256,768) -> permuted B^T: pcol(w,nt,l15) holds original col n = gate*256 + 32w + 2*l15 + grp,
// nt = gate*2+grp. Wave w then owns gate triples (z,r,h) for h-cols {32w+2*l15+grp}.
__global__ void wrperm_kernel(const float* __restrict__ in, u16* __restrict__ out) {
  int idx = blockIdx.x * blockDim.x + threadIdx.x;
  if (idx < 256 * 768) {
    int k = idx / 768, n = idx % 768;
    int gate = n >> 8, c = n & 255;
    int w = c >> 5, cc = c & 31, l15 = cc >> 1, grp = cc & 1;
    int nt = gate * 2 + grp;
    out[((((w * 6 + nt) << 4) + l15) << 8) + k] = f2b(in[idx]);
  }
}

// biasMod = bi + [br_z, br_r, 0]
__global__ void biasmod_kernel(const float* __restrict__ bi, const float* __restrict__ br,
                               float* __restrict__ bm) {
  int n = blockIdx.x * blockDim.x + threadIdx.x;
  if (n < 768) bm[n] = bi[n] + (n < 512 ? br[n] : 0.f);
}

// ---------------- gemm tile (256- or 512-thread blocks; tid<256 active) ----------------
// CASTA=1: A fp32, converted during staging (bit-identical to separate-cast path).
// MODE 0: A rows = bm*128+r, relu, C ldc=256.
// MODE 1: TCv=64: A rows = (2bm+(r>>6))*512+t0+(r&63); TCv=128: A rows = bm*512+t0+r.
//         C rows = bm*128+r, natural chunk layout (b, tl, n), ldc=768 (identical formula
//         for both TCv -- verified: (b*TCv+tl) == bm*128+r in each case).
template<int KT, int MODE, int CASTA, int TCv>
__device__ void gemm_tile(char* smem_c, const void* __restrict__ Av, const u16* __restrict__ Bt,
                          const float* __restrict__ bias, u16* __restrict__ C, int t0,
                          int bm, int bn) {
  constexpr int K = KT * 32;
  const u16* A = (const u16*)Av;
  const float* Af = (const float*)Av;
  u16* As = (u16*)smem_c;             // [128][40]
  u16* Bs = (u16*)(smem_c + 10240);   // [128][40]
  const int tid = threadIdx.x;
  const bool act = (tid < 256);
  const int lane = tid & 63, wid = tid >> 6;
  const int l15 = lane & 15, l4 = lane >> 4;
  const int qm = ((wid & 3) >> 1) * 64, qn = (wid & 1) * 64;

  const int c0 = tid & 255, c1 = (tid & 255) + 256;
  const int r0 = c0 >> 2, r1 = c1 >> 2;
  int ar0, ar1;
  if (MODE == 0) {
    ar0 = bm * 128 + r0;
    ar1 = bm * 128 + r1;
  } else if (TCv == 64) {
    ar0 = (2 * bm + (r0 >> 6)) * 512 + t0 + (r0 & 63);
    ar1 = (2 * bm + (r1 >> 6)) * 512 + t0 + (r1 & 63);
  } else {
    ar0 = bm * 512 + t0 + r0;
    ar1 = bm * 512 + t0 + r1;
  }
  const size_t ga0 = (size_t)ar0 * K + (c0 & 3) * 8;
  const size_t ga1 = (size_t)ar1 * K + (c1 & 3) * 8;
  const size_t gb0 = (size_t)(bn * 128 + r0) * K + (c0 & 3) * 8;
  const size_t gb1 = (size_t)(bn * 128 + r1) * K + (c1 & 3) * 8;
  const int sa0 = r0 * 40 + (c0 & 3) * 8;
  const int sa1 = r1 * 40 + (c1 & 3) * 8;

#define LOADA(ga, ko, dst)                                                       \
  if (CASTA) {                                                                   \
    const float* p = Af + (ga) + (ko);                                           \
    const f32x4 v0 = *(const f32x4*)(p);                                         \
    const f32x4 v1 = *(const f32x4*)(p + 4);                                     \
    (dst).x = pkbf(v0[0], v0[1]); (dst).y = pkbf(v0[2], v0[3]);                  \
    (dst).z = pkbf(v1[0], v1[1]); (dst).w = pkbf(v1[2], v1[3]);                  \
  } else {                                                                       \
    (dst) = *(const uint4*)(A + (ga) + (ko));                                    \
  }

  uint4 ra0 = {}, ra1 = {}, rb0 = {}, rb1 = {};
  if (act) {
    LOADA(ga0, 0, ra0);
    LOADA(ga1, 0, ra1);
    rb0 = *(const uint4*)(Bt + gb0);
    rb1 = *(const uint4*)(Bt + gb1);
  }
  f32x4 acc[4][4] = {};

  for (int kt = 0; kt < KT; ++kt) {
    __syncthreads();
    if (act) {
      *(uint4*)(As + sa0) = ra0;
      *(uint4*)(As + sa1) = ra1;
      *(uint4*)(Bs + sa0) = rb0;
      *(uint4*)(Bs + sa1) = rb1;
    }
    __syncthreads();
    if (act) {
      if (kt + 1 < KT) {
        const int ko = (kt + 1) * 32;
        LOADA(ga0, ko, ra0);
        LOADA(ga1, ko, ra1);
        rb0 = *(const uint4*)(Bt + gb0 + ko);
        rb1 = *(const uint4*)(Bt + gb1 + ko);
      }
      bf16x8 af[4], bfr[4];
#pragma unroll
      for (int mt = 0; mt < 4; ++mt)
        af[mt] = *(const bf16x8*)(As + (qm + mt * 16 + l15) * 40 + l4 * 8);
#pragma unroll
      for (int nt = 0; nt < 4; ++nt)
        bfr[nt] = *(const bf16x8*)(Bs + (qn + nt * 16 + l15) * 40 + l4 * 8);
#pragma unroll
      for (int mt = 0; mt < 4; ++mt)
#pragma unroll
        for (int nt = 0; nt < 4; ++nt)
          acc[mt][nt] = __builtin_amdgcn_mfma_f32_16x16x32_bf16(af[mt], bfr[nt], acc[mt][nt], 0, 0, 0);
    }
  }
#undef LOADA

  if (act) {
#pragma unroll
    for (int mt = 0; mt < 4; ++mt)
#pragma unroll
      for (int nt = 0; nt < 4; ++nt) {
        const int n = bn * 128 + qn + nt * 16 + l15;
        const float bv = bias[n];
#pragma unroll
        for (int j = 0; j < 4; ++j) {
          const int rloc = qm + mt * 16 + l4 * 4 + j;  // D: row=(lane>>4)*4+j, col=lane&15
          float v = acc[mt][nt][j] + bv;
          if (MODE == 0) {
            v = fmaxf(v, 0.f);
            C[(size_t)(bm * 128 + rloc) * 256 + n] = f2b(v);
          } else {
            C[((size_t)bm * 128 + rloc) * 768 + n] = f2b(v);
          }
        }
      }
  }
}

// prologue wrappers (256 threads)
__global__ __launch_bounds__(256) void gemm1_kernel(const float* __restrict__ x,
                                                    const u16* __restrict__ W1T,
                                                    const float* __restrict__ b1,
                                                    u16* __restrict__ h1) {
  __shared__ alignas(16) char smem_c[20480];
  gemm_tile<4, 0, 1, 64>(smem_c, x, W1T, b1, h1, 0, blockIdx.x, blockIdx.y);
}
template<int TCv>
__global__ __launch_bounds__(256) void gemm2_kernel(const u16* __restrict__ h1,
                                                    const u16* __restrict__ WkT,
                                                    const float* __restrict__ biasM,
                                                    u16* __restrict__ xg, int t0) {
  __shared__ alignas(16) char smem_c[20480];
  gemm_tile<8, 1, 0, TCv>(smem_c, h1, WkT, biasM, xg, t0, blockIdx.x, blockIdx.y);
}

// ---------------- fused GRU(chunk c) + gemm2(chunk c+1)  [R13 structure, TC templated] --------
// Blocks 0..15: GRU chunk c (R11 body, byte-identical math) reading xrd.
// Blocks 16..783: gemm2 tiles for chunk c+1 writing xwr (TCv=64: 1 tile each; 128: 2 tiles).
// 82KB LDS => 1 block/CU. Launch boundary = proven cheapest sync (R13 < R14 grid.sync,
// R15 atomic producer-consumer).
template<int TCv>
__global__ __launch_bounds__(512, 1) void fused_kernel(
    const u16* __restrict__ xrd, u16* __restrict__ xwr,
    const u16* __restrict__ WrP, const float* __restrict__ br,
    float* __restrict__ hstate, const u16* __restrict__ h1A,
    const u16* __restrict__ WkT, const float* __restrict__ biasM,
    int t0, int do_gemm) {
  __shared__ alignas(16) char smem_c[82048];
  const int tid = threadIdx.x;

  if (blockIdx.x < 16) {
    // ---------------- GRU part ----------------
    u16* hb0 = (u16*)smem_c;              // 16*264 u16 - ping (h bf16)
    u16* hb1 = (u16*)(smem_c + 8448);     // pong
    u16* xs0 = (u16*)(smem_c + 16896);    // 16*776 u16 xq stage - ping
    u16* xs1 = (u16*)(smem_c + 41728);    // pong
    const int g = blockIdx.x;
    const int lane = tid & 63, wid = tid >> 6;
    const int l15 = lane & 15, l4 = lane >> 4;

    bf16x8 bw[8][6];
#pragma unroll
    for (int kk = 0; kk < 8; ++kk)
#pragma unroll
      for (int nt = 0; nt < 6; ++nt)
        bw[kk][nt] = *(const bf16x8*)(WrP + ((((wid * 6 + nt) << 4) + l15) << 8) + kk * 32 + l4 * 8);

    const int cbase = wid * 32 + l15 * 2;
    const float brh0 = br[512 + cbase];
    const float brh1 = br[512 + cbase + 1];
    const int rs = tid >> 5, ksl = (tid & 31) * 8;
    const u16* xg_row = xrd + (size_t)(g * 16 + rs) * TCv * 768 + ksl;
    u16* xw0 = xs0 + rs * 776 + ksl;
    u16* xw1 = xs1 + rs * 776 + ksl;

    f32x4 h0v, h1v;
    if (t0 == 0) {
      h0v = {0.f, 0.f, 0.f, 0.f};
      h1v = {0.f, 0.f, 0.f, 0.f};
    } else {
#pragma unroll
      for (int j = 0; j < 4; ++j) {
        float2 ld = *(const float2*)(hstate + ((size_t)g * 16 + l4 * 4 + j) * 256 + cbase);
        h0v[j] = ld.x; h1v[j] = ld.y;
      }
    }
#pragma unroll
    for (int j = 0; j < 4; ++j)
      *(u32*)(hb0 + (l4 * 4 + j) * 264 + cbase) = pkbf(h0v[j], h1v[j]);

    {  // pre-stage step 0 into xs0
      const uint4 s0 = *(const uint4*)(xg_row);
      const uint4 s1 = *(const uint4*)(xg_row + 256);
      const uint4 s2 = *(const uint4*)(xg_row + 512);
      *(uint4*)(xw0) = s0;
      *(uint4*)(xw0 + 256) = s1;
      *(uint4*)(xw0 + 512) = s2;
    }
    __syncthreads();

#define GRU_STEP(SRC, DST, XRD, XWR, TL)                                                    \
  {                                                                                         \
    const int tn = ((TL) + 1 < TCv) ? ((TL) + 1) : (TCv - 1);                               \
    const u16* xq = xg_row + (size_t)tn * 768;                                              \
    const uint4 s0 = *(const uint4*)(xq);                                                   \
    const uint4 s1 = *(const uint4*)(xq + 256);                                             \
    const uint4 s2 = *(const uint4*)(xq + 512);                                             \
    f32x4 a0 = {}, a2 = {}, a4 = {};                                                        \
    _Pragma("unroll")                                                                       \
    for (int kk = 0; kk < 8; ++kk) {                                                        \
      const bf16x8 a = *(const bf16x8*)((SRC) + l15 * 264 + kk * 32 + l4 * 8);              \
      a0 = __builtin_amdgcn_mfma_f32_16x16x32_bf16(a, bw[kk][0], a0, 0, 0, 0);              \
      a2 = __builtin_amdgcn_mfma_f32_16x16x32_bf16(a, bw[kk][2], a2, 0, 0, 0);              \
      a4 = __builtin_amdgcn_mfma_f32_16x16x32_bf16(a, bw[kk][4], a4, 0, 0, 0);              \
    }                                                                                       \
    u32 xz_[4], xr_[4], xh_[4];                                                             \
    _Pragma("unroll")                                                                       \
    for (int j = 0; j < 4; ++j) {                                                           \
      const u16* xr2 = (XRD) + (l4 * 4 + j) * 776 + cbase;                                  \
      xz_[j] = *(const u32*)(xr2);                                                          \
      xr_[j] = *(const u32*)(xr2 + 256);                                                    \
      xh_[j] = *(const u32*)(xr2 + 512);                                                    \
    }                                                                                       \
    f32x4 a1 = {}, a3 = {}, a5 = {};                                                        \
    _Pragma("unroll")                                                                       \
    for (int kk = 0; kk < 8; ++kk) {                                                        \
      const bf16x8 a = *(const bf16x8*)((SRC) + l15 * 264 + kk * 32 + l4 * 8);              \
      a1 = __builtin_amdgcn_mfma_f32_16x16x32_bf16(a, bw[kk][1], a1, 0, 0, 0);              \
      a3 = __builtin_amdgcn_mfma_f32_16x16x32_bf16(a, bw[kk][3], a3, 0, 0, 0);              \
      a5 = __builtin_amdgcn_mfma_f32_16x16x32_bf16(a, bw[kk][5], a5, 0, 0, 0);              \
    }                                                                                       \
    *(uint4*)(XWR) = s0;                                                                    \
    *(uint4*)((XWR) + 256) = s1;                                                            \
    *(uint4*)((XWR) + 512) = s2;                                                            \
    _Pragma("unroll")                                                                       \
    for (int j = 0; j < 4; ++j) {                                                           \
      const float z0 = sigm(blo(xz_[j]) + a0[j]);                                           \
      const float r0 = sigm(blo(xr_[j]) + a2[j]);                                           \
      const float hh0 = fmaxf(fmaf(r0, a4[j] + brh0, blo(xh_[j])), 0.f);                    \
      h0v[j] = fmaf(z0, h0v[j] - hh0, hh0);                                                 \
    }                                                                                       \
    _Pragma("unroll")                                                                       \
    for (int j = 0; j < 4; ++j) {                                                           \
      const float z1 = sigm(bhi(xz_[j]) + a1[j]);                                           \
      const float r1 = sigm(bhi(xr_[j]) + a3[j]);                                           \
      const float hh1 = fmaxf(fmaf(r1, a5[j] + brh1, bhi(xh_[j])), 0.f);                    \
      h1v[j] = fmaf(z1, h1v[j] - hh1, hh1);                                                 \
      *(u32*)((DST) + (l4 * 4 + j) * 264 + cbase) = pkbf(h0v[j], h1v[j]);                   \
    }                                                                                       \
    __syncthreads();                                                                        \
  }

    for (int tl = 0; tl < TCv; tl += 2) {
      GRU_STEP(hb0, hb1, xs0, xw1, tl);
      GRU_STEP(hb1, hb0, xs1, xw0, tl + 1);
    }
#undef GRU_STEP

#pragma unroll
    for (int j = 0; j < 4; ++j) {
      float2 st = {h0v[j], h1v[j]};
      *(float2*)(hstate + ((size_t)g * 16 + l4 * 4 + j) * 256 + cbase) = st;
    }
  } else {
    // ---------------- gemm2 part (next chunk) ----------------
    if (!do_gemm) return;
    constexpr int NT = (TCv == 64) ? 768 : 1536;
    const int t0g = t0 + TCv;
    for (int tix = (int)blockIdx.x - 16; tix < NT; tix += 768) {
      const int bm = (TCv == 64) ? (tix & 127) : (tix & 255);
      const int bn = (TCv == 64) ? (tix >> 7) : (tix >> 8);
      gemm_tile<8, 1, 0, TCv>(smem_c, h1A, WkT, biasM, xwr, t0g, bm, bn);
    }
  }
}

// ---------------- output: y = [h,h] @ W2 + b2 = h @ (W2_top + W2_bot) + b2 ----------------
__global__ void out_kernel(const float* __restrict__ h, const float* __restrict__ W2,
                           const float* __restrict__ b2, float* __restrict__ y) {
  const int bb = blockIdx.x, j = threadIdx.x;  // 256 blocks x 128 threads
  const float* hr = h + (size_t)bb * 256;
  float s = b2[j];
  for (int i = 0; i < 256; ++i)
    s = fmaf(hr[i], W2[i * 128 + j] + W2[(i + 256) * 128 + j], s);
  y[(size_t)bb * 128 + j] = s;
}

extern "C" void kernel_launch(void* const* d_in, const int* in_sizes, int n_in,
                              void* d_out, int out_size, void* d_ws, size_t ws_size,
                              hipStream_t stream) {
  const float* x  = (const float*)d_in[0];
  const float* W1 = (const float*)d_in[1];
  const float* b1 = (const float*)d_in[2];
  const float* Wk = (const float*)d_in[3];
  const float* Wr = (const float*)d_in[4];
  const float* bi = (const float*)d_in[5];
  const float* br = (const float*)d_in[6];
  const float* W2 = (const float*)d_in[7];
  const float* b2 = (const float*)d_in[8];
  float* y = (float*)d_out;

  // TC=128 path needs 168.9 MB; TC=64 (R13) path needs 118.6 MB. Select by ws_size
  // (fixed across calls -> deterministic).
  const size_t NEED128 = 67108864ull + 2 * 50331648ull + 65536ull + 2 * 393216ull +
                         262144ull + 4096ull;
  const size_t NEED64  = 67108864ull + 2 * 25165824ull + 65536ull + 2 * 393216ull +
                         262144ull + 4096ull;
  if (ws_size < NEED64) return;
  const bool big = (ws_size >= NEED128);
  const size_t xgsz = big ? 50331648ull : 25165824ull;

  char* ws = (char*)d_ws;
  u16* h1    = (u16*)ws;  ws += 67108864;   // (131072,256) bf16
  u16* xg0   = (u16*)ws;  ws += xgsz;       // (256,TC,768) bf16 chunk buffer 0
  u16* xg1   = (u16*)ws;  ws += xgsz;       // chunk buffer 1
  u16* W1T   = (u16*)ws;  ws += 65536;      // (256,128) bf16
  u16* WkT   = (u16*)ws;  ws += 393216;     // (768,256) bf16
  u16* WrP   = (u16*)ws;  ws += 393216;     // permuted Wr^T (768,256) bf16
  float* hstate = (float*)ws; ws += 262144; // (256,256) f32 carried GRU state
  float* biasM  = (float*)ws;               // 768 f32

  tcast_kernel<<<128, 256, 0, stream>>>(W1, W1T, 128, 256);
  tcast_kernel<<<768, 256, 0, stream>>>(Wk, WkT, 256, 768);
  wrperm_kernel<<<768, 256, 0, stream>>>(Wr, WrP);
  biasmod_kernel<<<3, 256, 0, stream>>>(bi, br, biasM);
  gemm1_kernel<<<dim3(1024, 2), 256, 0, stream>>>(x, W1T, b1, h1);
  if (big) {
    gemm2_kernel<128><<<dim3(256, 6), 256, 0, stream>>>(h1, WkT, biasM, xg0, 0);  // chunk 0
    for (int c = 0; c < 4; ++c) {
      const u16* xrd = (c & 1) ? xg1 : xg0;
      u16* xwr = (c & 1) ? xg0 : xg1;
      fused_kernel<128><<<784, 512, 0, stream>>>(xrd, xwr, WrP, br, hstate, h1, WkT, biasM,
                                                 c * 128, (c < 3) ? 1 : 0);
    }
  } else {
    gemm2_kernel<64><<<dim3(128, 6), 256, 0, stream>>>(h1, WkT, biasM, xg0, 0);  // chunk 0
    for (int c = 0; c < 8; ++c) {
      const u16* xrd = (c & 1) ? xg1 : xg0;
      u16* xwr = (c & 1) ? xg0 : xg1;
      fused_kernel<64><<<784, 512, 0, stream>>>(xrd, xwr, WrP, br, hstate, h1, WkT, biasM,
                                                c * 64, (c < 7) ? 1 : 0);
    }
  }
  out_kernel<<<256, 128, 0, stream>>>(hstate, W2, b2, y);
}

// Round 17
// 948.379 us; speedup vs baseline: 1.2965x; 1.0182x over previous
//
#include <hip/hip_runtime.h>

typedef unsigned short u16;
typedef unsigned int u32;
typedef float f32x4 __attribute__((ext_vector_type(4)));
typedef __bf16 bf16x8 __attribute__((ext_vector_type(8)));

// B=256, T=512, FIN=128, H=256, 3H=768
#define TB 256
#define TT 512

__device__ __forceinline__ u16 f2b(float f) {
  u32 x = __float_as_uint(f);
  return (u16)((x + 0x7fffu + ((x >> 16) & 1u)) >> 16);
}
__device__ __forceinline__ u32 pkbf(float a, float b) {  // RNE, bit-identical to f2b pair pack
  u32 r;
  asm("v_cvt_pk_bf16_f32 %0, %1, %2" : "=v"(r) : "v"(a), "v"(b));
  return r;
}
__device__ __forceinline__ float blo(u32 u) { return __uint_as_float(u << 16); }
__device__ __forceinline__ float bhi(u32 u) { return __uint_as_float(u & 0xffff0000u); }
__device__ __forceinline__ float sigm(float x) {
  return __builtin_amdgcn_rcpf(1.f + __expf(-x));
}

// ---------------- fused weight prep: W1^T, Wk^T, Wr-permute, biasMod ----------------
__global__ __launch_bounds__(256) void prep_kernel(
    const float* __restrict__ W1, const float* __restrict__ Wk, const float* __restrict__ Wr,
    const float* __restrict__ bi, const float* __restrict__ br,
    u16* __restrict__ W1T, u16* __restrict__ WkT, u16* __restrict__ WrP,
    float* __restrict__ biasM) {
  const int gt = blockIdx.x * 256 + threadIdx.x;  // 512 blocks -> 131072 threads
  if (gt < 32768) {  // W1 (128,256) -> W1T (256,128)
    const int k = gt >> 8, n = gt & 255;
    W1T[n * 128 + k] = f2b(W1[gt]);
  }
  for (int idx = gt; idx < 196608; idx += 131072) {  // Wk (256,768) -> WkT (768,256)
    const int k = idx / 768, n = idx % 768;
    WkT[(size_t)n * 256 + k] = f2b(Wk[idx]);
  }
  for (int idx = gt; idx < 196608; idx += 131072) {  // Wr -> permuted WrP
    const int k = idx / 768, n = idx % 768;
    const int gate = n >> 8, c = n & 255;
    const int w = c >> 5, cc = c & 31, l15 = cc >> 1, grp = cc & 1;
    const int nt = gate * 2 + grp;
    WrP[((((w * 6 + nt) << 4) + l15) << 8) + k] = f2b(Wr[idx]);
  }
  if (gt < 768) biasM[gt] = bi[gt] + (gt < 512 ? br[gt] : 0.f);
}

// ---------------- gemm tile (256- or 512-thread blocks; tid<256 active) ----------------
// CASTA=1: A fp32, converted during staging (bit-identical to separate-cast path).
// MODE 0: A rows = bm*128+r, relu, C ldc=256.
// MODE 1: TCv=64: A rows = (2bm+(r>>6))*512+t0+(r&63); TCv=128: A rows = bm*512+t0+r.
//         C rows = bm*128+r, natural chunk layout (b, tl, n), ldc=768 (xg chunk).
template<int KT, int MODE, int CASTA, int TCv>
__device__ void gemm_tile(char* smem_c, const void* __restrict__ Av, const u16* __restrict__ Bt,
                          const float* __restrict__ bias, u16* __restrict__ C, int t0,
                          int bm, int bn) {
  constexpr int K = KT * 32;
  const u16* A = (const u16*)Av;
  const float* Af = (const float*)Av;
  u16* As = (u16*)smem_c;             // [128][40]
  u16* Bs = (u16*)(smem_c + 10240);   // [128][40]
  const int tid = threadIdx.x;
  const bool act = (tid < 256);
  const int lane = tid & 63, wid = tid >> 6;
  const int l15 = lane & 15, l4 = lane >> 4;
  const int qm = ((wid & 3) >> 1) * 64, qn = (wid & 1) * 64;

  const int c0 = tid & 255, c1 = (tid & 255) + 256;
  const int r0 = c0 >> 2, r1 = c1 >> 2;
  int ar0, ar1;
  if (MODE == 0) {
    ar0 = bm * 128 + r0;
    ar1 = bm * 128 + r1;
  } else if (TCv == 64) {
    ar0 = (2 * bm + (r0 >> 6)) * 512 + t0 + (r0 & 63);
    ar1 = (2 * bm + (r1 >> 6)) * 512 + t0 + (r1 & 63);
  } else {
    ar0 = bm * 512 + t0 + r0;
    ar1 = bm * 512 + t0 + r1;
  }
  const size_t ga0 = (size_t)ar0 * K + (c0 & 3) * 8;
  const size_t ga1 = (size_t)ar1 * K + (c1 & 3) * 8;
  const size_t gb0 = (size_t)(bn * 128 + r0) * K + (c0 & 3) * 8;
  const size_t gb1 = (size_t)(bn * 128 + r1) * K + (c1 & 3) * 8;
  const int sa0 = r0 * 40 + (c0 & 3) * 8;
  const int sa1 = r1 * 40 + (c1 & 3) * 8;

#define LOADA(ga, ko, dst)                                                       \
  if (CASTA) {                                                                   \
    const float* p = Af + (ga) + (ko);                                           \
    const f32x4 v0 = *(const f32x4*)(p);                                         \
    const f32x4 v1 = *(const f32x4*)(p + 4);                                     \
    (dst).x = pkbf(v0[0], v0[1]); (dst).y = pkbf(v0[2], v0[3]);                  \
    (dst).z = pkbf(v1[0], v1[1]); (dst).w = pkbf(v1[2], v1[3]);                  \
  } else {                                                                       \
    (dst) = *(const uint4*)(A + (ga) + (ko));                                    \
  }

  uint4 ra0 = {}, ra1 = {}, rb0 = {}, rb1 = {};
  if (act) {
    LOADA(ga0, 0, ra0);
    LOADA(ga1, 0, ra1);
    rb0 = *(const uint4*)(Bt + gb0);
    rb1 = *(const uint4*)(Bt + gb1);
  }
  f32x4 acc[4][4] = {};

  for (int kt = 0; kt < KT; ++kt) {
    __syncthreads();
    if (act) {
      *(uint4*)(As + sa0) = ra0;
      *(uint4*)(As + sa1) = ra1;
      *(uint4*)(Bs + sa0) = rb0;
      *(uint4*)(Bs + sa1) = rb1;
    }
    __syncthreads();
    if (act) {
      if (kt + 1 < KT) {
        const int ko = (kt + 1) * 32;
        LOADA(ga0, ko, ra0);
        LOADA(ga1, ko, ra1);
        rb0 = *(const uint4*)(Bt + gb0 + ko);
        rb1 = *(const uint4*)(Bt + gb1 + ko);
      }
      bf16x8 af[4], bfr[4];
#pragma unroll
      for (int mt = 0; mt < 4; ++mt)
        af[mt] = *(const bf16x8*)(As + (qm + mt * 16 + l15) * 40 + l4 * 8);
#pragma unroll
      for (int nt = 0; nt < 4; ++nt)
        bfr[nt] = *(const bf16x8*)(Bs + (qn + nt * 16 + l15) * 40 + l4 * 8);
#pragma unroll
      for (int mt = 0; mt < 4; ++mt)
#pragma unroll
        for (int nt = 0; nt < 4; ++nt)
          acc[mt][nt] = __builtin_amdgcn_mfma_f32_16x16x32_bf16(af[mt], bfr[nt], acc[mt][nt], 0, 0, 0);
    }
  }
#undef LOADA

  if (act) {
#pragma unroll
    for (int mt = 0; mt < 4; ++mt)
#pragma unroll
      for (int nt = 0; nt < 4; ++nt) {
        const int n = bn * 128 + qn + nt * 16 + l15;
        const float bv = bias[n];
#pragma unroll
        for (int j = 0; j < 4; ++j) {
          const int rloc = qm + mt * 16 + l4 * 4 + j;  // D: row=(lane>>4)*4+j, col=lane&15
          float v = acc[mt][nt][j] + bv;
          if (MODE == 0) {
            v = fmaxf(v, 0.f);
            C[(size_t)(bm * 128 + rloc) * 256 + n] = f2b(v);
          } else {
            C[((size_t)bm * 128 + rloc) * 768 + n] = f2b(v);
          }
        }
      }
  }
}

// prologue wrappers (256 threads)
__global__ __launch_bounds__(256) void gemm1_kernel(const float* __restrict__ x,
                                                    const u16* __restrict__ W1T,
                                                    const float* __restrict__ b1,
                                                    u16* __restrict__ h1) {
  __shared__ alignas(16) char smem_c[20480];
  gemm_tile<4, 0, 1, 64>(smem_c, x, W1T, b1, h1, 0, blockIdx.x, blockIdx.y);
}
// gemm1 restricted to t-ranges 0,1 (tiles with bm&3 in {0,1}): bm = (bx&255)*4 + (bx>>8)
__global__ __launch_bounds__(256) void gemm1r_kernel(const float* __restrict__ x,
                                                     const u16* __restrict__ W1T,
                                                     const float* __restrict__ b1,
                                                     u16* __restrict__ h1) {
  __shared__ alignas(16) char smem_c[20480];
  const int bm = (blockIdx.x & 255) * 4 + (blockIdx.x >> 8);
  gemm_tile<4, 0, 1, 64>(smem_c, x, W1T, b1, h1, 0, bm, blockIdx.y);
}
template<int TCv>
__global__ __launch_bounds__(256) void gemm2_kernel(const u16* __restrict__ h1,
                                                    const u16* __restrict__ WkT,
                                                    const float* __restrict__ biasM,
                                                    u16* __restrict__ xg, int t0) {
  __shared__ alignas(16) char smem_c[20480];
  gemm_tile<8, 1, 0, TCv>(smem_c, h1, WkT, biasM, xg, t0, blockIdx.x, blockIdx.y);
}

// ---------------- fused GRU(chunk c) + gemm2(chunk c+1) [+ gemm1 range c+2] ----------------
// Blocks 0..15: GRU chunk c (byte-identical math) reading xrd.
// Blocks 16..783: gemm2 tiles for chunk c+1 (ng2 tiles) then gemm1 tiles for t-range c+2
// (ng1 tiles, big path c<2 only). 82KB LDS => 1 block/CU. Launch boundary = proven cheapest
// sync (R13 < R14 grid.sync < R15 atomic producer-consumer).
template<int TCv>
__global__ __launch_bounds__(512, 1) void fused_kernel(
    const u16* __restrict__ xrd, u16* __restrict__ xwr,
    const u16* __restrict__ WrP, const float* __restrict__ br,
    float* __restrict__ hstate, const u16* __restrict__ h1A,
    const u16* __restrict__ WkT, const float* __restrict__ biasM,
    const float* __restrict__ x, const u16* __restrict__ W1T,
    const float* __restrict__ b1, u16* __restrict__ h1w,
    int t0, int ng2, int g1range) {
  __shared__ alignas(16) char smem_c[82048];
  const int tid = threadIdx.x;

  if (blockIdx.x < 16) {
    // ---------------- GRU part ----------------
    u16* hb0 = (u16*)smem_c;              // 16*264 u16 - ping (h bf16)
    u16* hb1 = (u16*)(smem_c + 8448);     // pong
    u16* xs0 = (u16*)(smem_c + 16896);    // 16*776 u16 xq stage - ping
    u16* xs1 = (u16*)(smem_c + 41728);    // pong
    const int g = blockIdx.x;
    const int lane = tid & 63, wid = tid >> 6;
    const int l15 = lane & 15, l4 = lane >> 4;

    bf16x8 bw[8][6];
#pragma unroll
    for (int kk = 0; kk < 8; ++kk)
#pragma unroll
      for (int nt = 0; nt < 6; ++nt)
        bw[kk][nt] = *(const bf16x8*)(WrP + ((((wid * 6 + nt) << 4) + l15) << 8) + kk * 32 + l4 * 8);

    const int cbase = wid * 32 + l15 * 2;
    const float brh0 = br[512 + cbase];
    const float brh1 = br[512 + cbase + 1];
    const int rs = tid >> 5, ksl = (tid & 31) * 8;
    const u16* xg_row = xrd + (size_t)(g * 16 + rs) * TCv * 768 + ksl;
    u16* xw0 = xs0 + rs * 776 + ksl;
    u16* xw1 = xs1 + rs * 776 + ksl;

    f32x4 h0v, h1v;
    if (t0 == 0) {
      h0v = {0.f, 0.f, 0.f, 0.f};
      h1v = {0.f, 0.f, 0.f, 0.f};
    } else {
#pragma unroll
      for (int j = 0; j < 4; ++j) {
        float2 ld = *(const float2*)(hstate + ((size_t)g * 16 + l4 * 4 + j) * 256 + cbase);
        h0v[j] = ld.x; h1v[j] = ld.y;
      }
    }
#pragma unroll
    for (int j = 0; j < 4; ++j)
      *(u32*)(hb0 + (l4 * 4 + j) * 264 + cbase) = pkbf(h0v[j], h1v[j]);

    {  // pre-stage step 0 into xs0
      const uint4 s0 = *(const uint4*)(xg_row);
      const uint4 s1 = *(const uint4*)(xg_row + 256);
      const uint4 s2 = *(const uint4*)(xg_row + 512);
      *(uint4*)(xw0) = s0;
      *(uint4*)(xw0 + 256) = s1;
      *(uint4*)(xw0 + 512) = s2;
    }
    __syncthreads();

#define GRU_STEP(SRC, DST, XRD, XWR, TL)                                                    \
  {                                                                                         \
    const int tn = ((TL) + 1 < TCv) ? ((TL) + 1) : (TCv - 1);                               \
    const u16* xq = xg_row + (size_t)tn * 768;                                              \
    const uint4 s0 = *(const uint4*)(xq);                                                   \
    const uint4 s1 = *(const uint4*)(xq + 256);                                             \
    const uint4 s2 = *(const uint4*)(xq + 512);                                             \
    f32x4 a0 = {}, a2 = {}, a4 = {};                                                        \
    _Pragma("unroll")                                                                       \
    for (int kk = 0; kk < 8; ++kk) {                                                        \
      const bf16x8 a = *(const bf16x8*)((SRC) + l15 * 264 + kk * 32 + l4 * 8);              \
      a0 = __builtin_amdgcn_mfma_f32_16x16x32_bf16(a, bw[kk][0], a0, 0, 0, 0);              \
      a2 = __builtin_amdgcn_mfma_f32_16x16x32_bf16(a, bw[kk][2], a2, 0, 0, 0);              \
      a4 = __builtin_amdgcn_mfma_f32_16x16x32_bf16(a, bw[kk][4], a4, 0, 0, 0);              \
    }                                                                                       \
    u32 xz_[4], xr_[4], xh_[4];                                                             \
    _Pragma("unroll")                                                                       \
    for (int j = 0; j < 4; ++j) {                                                           \
      const u16* xr2 = (XRD) + (l4 * 4 + j) * 776 + cbase;                                  \
      xz_[j] = *(const u32*)(xr2);                                                          \
      xr_[j] = *(const u32*)(xr2 + 256);                                                    \
      xh_[j] = *(const u32*)(xr2 + 512);                                                    \
    }                                                                                       \
    f32x4 a1 = {}, a3 = {}, a5 = {};                                                        \
    _Pragma("unroll")                                                                       \
    for (int kk = 0; kk < 8; ++kk) {                                                        \
      const bf16x8 a = *(const bf16x8*)((SRC) + l15 * 264 + kk * 32 + l4 * 8);              \
      a1 = __builtin_amdgcn_mfma_f32_16x16x32_bf16(a, bw[kk][1], a1, 0, 0, 0);              \
      a3 = __builtin_amdgcn_mfma_f32_16x16x32_bf16(a, bw[kk][3], a3, 0, 0, 0);              \
      a5 = __builtin_amdgcn_mfma_f32_16x16x32_bf16(a, bw[kk][5], a5, 0, 0, 0);              \
    }                                                                                       \
    *(uint4*)(XWR) = s0;                                                                    \
    *(uint4*)((XWR) + 256) = s1;                                                            \
    *(uint4*)((XWR) + 512) = s2;                                                            \
    _Pragma("unroll")                                                                       \
    for (int j = 0; j < 4; ++j) {                                                           \
      const float z0 = sigm(blo(xz_[j]) + a0[j]);                                           \
      const float r0 = sigm(blo(xr_[j]) + a2[j]);                                           \
      const float hh0 = fmaxf(fmaf(r0, a4[j] + brh0, blo(xh_[j])), 0.f);                    \
      h0v[j] = fmaf(z0, h0v[j] - hh0, hh0);                                                 \
    }                                                                                       \
    _Pragma("unroll")                                                                       \
    for (int j = 0; j < 4; ++j) {                                                           \
      const float z1 = sigm(bhi(xz_[j]) + a1[j]);                                           \
      const float r1 = sigm(bhi(xr_[j]) + a3[j]);                                           \
      const float hh1 = fmaxf(fmaf(r1, a5[j] + brh1, bhi(xh_[j])), 0.f);                    \
      h1v[j] = fmaf(z1, h1v[j] - hh1, hh1);                                                 \
      *(u32*)((DST) + (l4 * 4 + j) * 264 + cbase) = pkbf(h0v[j], h1v[j]);                   \
    }                                                                                       \
    __syncthreads();                                                                        \
  }

    for (int tl = 0; tl < TCv; tl += 2) {
      GRU_STEP(hb0, hb1, xs0, xw1, tl);
      GRU_STEP(hb1, hb0, xs1, xw0, tl + 1);
    }
#undef GRU_STEP

#pragma unroll
    for (int j = 0; j < 4; ++j) {
      float2 st = {h0v[j], h1v[j]};
      *(float2*)(hstate + ((size_t)g * 16 + l4 * 4 + j) * 256 + cbase) = st;
    }
  } else {
    // ---------------- gemm part: gemm2 chunk c+1, then gemm1 t-range c+2 ----------------
    const int t0g = t0 + TCv;
    const int ntot = ng2 + ((g1range >= 0) ? 512 : 0);
    for (int tix = (int)blockIdx.x - 16; tix < ntot; tix += 768) {
      if (tix < ng2) {
        const int bm = (TCv == 64) ? (tix & 127) : (tix & 255);
        const int bn = (TCv == 64) ? (tix >> 7) : (tix >> 8);
        gemm_tile<8, 1, 0, TCv>(smem_c, h1A, WkT, biasM, xwr, t0g, bm, bn);
      } else {
        const int sub = tix - ng2;  // 0..511
        const int bmg = (sub >> 1) * 4 + g1range;
        gemm_tile<4, 0, 1, 64>(smem_c, x, W1T, b1, h1w, 0, bmg, sub & 1);
      }
    }
  }
}

// ---------------- output: y = [h,h] @ W2 + b2 = h @ (W2_top + W2_bot) + b2 ----------------
__global__ void out_kernel(const float* __restrict__ h, const float* __restrict__ W2,
                           const float* __restrict__ b2, float* __restrict__ y) {
  const int bb = blockIdx.x, j = threadIdx.x;  // 256 blocks x 128 threads
  const float* hr = h + (size_t)bb * 256;
  float s = b2[j];
  for (int i = 0; i < 256; ++i)
    s = fmaf(hr[i], W2[i * 128 + j] + W2[(i + 256) * 128 + j], s);
  y[(size_t)bb * 128 + j] = s;
}

extern "C" void kernel_launch(void* const* d_in, const int* in_sizes, int n_in,
                              void* d_out, int out_size, void* d_ws, size_t ws_size,
                              hipStream_t stream) {
  const float* x  = (const float*)d_in[0];
  const float* W1 = (const float*)d_in[1];
  const float* b1 = (const float*)d_in[2];
  const float* Wk = (const float*)d_in[3];
  const float* Wr = (const float*)d_in[4];
  const float* bi = (const float*)d_in[5];
  const float* br = (const float*)d_in[6];
  const float* W2 = (const float*)d_in[7];
  const float* b2 = (const float*)d_in[8];
  float* y = (float*)d_out;

  // TC=128 path needs 168.9 MB; TC=64 fallback needs 118.6 MB. Select by ws_size
  // (fixed across calls -> deterministic).
  const size_t NEED128 = 67108864ull + 2 * 50331648ull + 65536ull + 2 * 393216ull +
                         262144ull + 4096ull;
  const size_t NEED64  = 67108864ull + 2 * 25165824ull + 65536ull + 2 * 393216ull +
                         262144ull + 4096ull;
  if (ws_size < NEED64) return;
  const bool big = (ws_size >= NEED128);
  const size_t xgsz = big ? 50331648ull : 25165824ull;

  char* ws = (char*)d_ws;
  u16* h1    = (u16*)ws;  ws += 67108864;   // (131072,256) bf16
  u16* xg0   = (u16*)ws;  ws += xgsz;       // (256,TC,768) bf16 chunk buffer 0
  u16* xg1   = (u16*)ws;  ws += xgsz;       // chunk buffer 1
  u16* W1T   = (u16*)ws;  ws += 65536;      // (256,128) bf16
  u16* WkT   = (u16*)ws;  ws += 393216;     // (768,256) bf16
  u16* WrP   = (u16*)ws;  ws += 393216;     // permuted Wr^T (768,256) bf16
  float* hstate = (float*)ws; ws += 262144; // (256,256) f32 carried GRU state
  float* biasM  = (float*)ws;               // 768 f32

  prep_kernel<<<512, 256, 0, stream>>>(W1, Wk, Wr, bi, br, W1T, WkT, WrP, biasM);
  if (big) {
    gemm1r_kernel<<<dim3(512, 2), 256, 0, stream>>>(x, W1T, b1, h1);  // t-ranges 0,1 only
    gemm2_kernel<128><<<dim3(256, 6), 256, 0, stream>>>(h1, WkT, biasM, xg0, 0);  // chunk 0
    for (int c = 0; c < 4; ++c) {
      const u16* xrd = (c & 1) ? xg1 : xg0;
      u16* xwr = (c & 1) ? xg0 : xg1;
      fused_kernel<128><<<784, 512, 0, stream>>>(
          xrd, xwr, WrP, br, hstate, h1, WkT, biasM, x, W1T, b1, h1,
          c * 128, (c < 3) ? 1536 : 0, (c < 2) ? (c + 2) : -1);
    }
  } else {
    gemm1_kernel<<<dim3(1024, 2), 256, 0, stream>>>(x, W1T, b1, h1);
    gemm2_kernel<64><<<dim3(128, 6), 256, 0, stream>>>(h1, WkT, biasM, xg0, 0);  // chunk 0
    for (int c = 0; c < 8; ++c) {
      const u16* xrd = (c & 1) ? xg1 : xg0;
      u16* xwr = (c & 1) ? xg0 : xg1;
      fused_kernel<64><<<784, 512, 0, stream>>>(
          xrd, xwr, WrP, br, hstate, h1, WkT, biasM, x, W1T, b1, h1,
          c * 64, (c < 7) ? 768 : 0, -1);
    }
  }
  out_kernel<<<256, 128, 0, stream>>>(hstate, W2, b2, y);
}